// Round 6
// baseline (3559.372 us; speedup 1.0000x reference)
//
#include <hip/hip_runtime.h>
#include <hip/hip_bf16.h>
#include <hip/hip_fp16.h>
#include <stdint.h>

typedef short bf16x8 __attribute__((ext_vector_type(8)));
typedef unsigned short u16x8 __attribute__((ext_vector_type(8)));
typedef float f32x4  __attribute__((ext_vector_type(4)));
typedef __hip_bfloat16 bf16;
typedef unsigned long long u64;

#define MFMA16(a,b,c) __builtin_amdgcn_mfma_f32_16x16x32_bf16((a),(b),(c),0,0,0)

__device__ __forceinline__ float bf2f(bf16 x){ return __bfloat162float(x); }
__device__ __forceinline__ bf16  f2bf(float x){ return __float2bfloat16(x); }
__device__ __forceinline__ short f2bs(float x){ bf16 t = __float2bfloat16(x); return *(short*)&t; }
__device__ __forceinline__ float bs2f(short s){ bf16 t; *(short*)&t = s; return __bfloat162float(t); }
__device__ __forceinline__ float h2f(unsigned short u){ __half t; *(unsigned short*)&t = u; return __half2float(t); }
// sanitize raw f32 inputs: kill NaN/inf
__device__ __forceinline__ float sf(float x){ return (fabsf(x) < 1e30f) ? x : 0.f; }

// Problem: B=128, L=256, H=512, OUT=256. All I/O float32. Chunked: 8 x 32 steps.
#define NB   128
#define NL   256
#define CH   32     // steps per chunk
#define MCH  4096   // rows per chunk = CH*NB
#define NQ   8      // chunks

#define RLXA __ATOMIC_RELAXED, __HIP_MEMORY_SCOPE_AGENT

// ---------------- weight preprocessing (f32 in -> bf16 internal) ----------------

__global__ void build_wcatT(const float* __restrict__ Wx, const float* __restrict__ Wm,
                            bf16* __restrict__ dst) {
    int i = blockIdx.x * 256 + threadIdx.x;
    if (i >= 1536 * 1024) return;
    int n = i >> 10, k = i & 1023;
    float v = (k < 512) ? Wx[k * 1536 + n] : Wm[(k - 512) * 1536 + n];
    dst[i] = f2bf(sf(v));
}

__global__ void transpose_f2b(const float* __restrict__ src, bf16* __restrict__ dst,
                              int R, int C) {
    int i = blockIdx.x * 256 + threadIdx.x;
    if (i >= R * C) return;
    int r = i % R, c = i / R;
    dst[i] = f2bf(sf(src[r * C + c]));
}

// ---------------- x-path (h-independent) ----------------

__global__ void xmean_kernel(const int* __restrict__ mask, const float* __restrict__ Cmat,
                             float* __restrict__ xmean) {
    int g = blockIdx.x * 256 + threadIdx.x;   // (b,h)
    int b = g >> 9, h = g & 511;
    float s = 0.f, cnt = 0.f;
    for (int l = 0; l < NL; ++l) {
        int m = mask[(size_t)((b << 8) + l) * 512 + h];
        if (m) { s += sf(Cmat[(l << 9) + h]); cnt += 1.f; }
    }
    xmean[g] = s / fmaxf(cnt, 1.f);
}

__global__ void prep_kernel(const int* __restrict__ mask, const float* __restrict__ Cmat,
                            const float* __restrict__ t_in,
                            const float* __restrict__ w_gx, const float* __restrict__ b_gx,
                            const float* __restrict__ xmean,
                            float* __restrict__ xlastC, float* __restrict__ dprevC,
                            float* __restrict__ mprevC, float* __restrict__ tprevC,
                            bf16* __restrict__ Xcat,   // (4096,1024) l-major: [x_hat|m]
                            bf16* __restrict__ Dbuf,   // (4096,512) l-major: delta
                            int q) {
    int g = blockIdx.x * 256 + threadIdx.x;
    int b = g >> 9, h = g & 511;
    float wg = sf(w_gx[h]), bg = sf(b_gx[h]);
    float xm = xmean[g];
    float xlast, dprev, mprev, tprev;
    if (q == 0) { xlast = xm; dprev = 0.f; mprev = 1.f; tprev = 0.f; }
    else { xlast = xlastC[g]; dprev = dprevC[g]; mprev = mprevC[g]; tprev = tprevC[g]; }
    for (int ll = 0; ll < CH; ++ll) {
        int l = q * CH + ll;
        float tc = sf(t_in[(b << 8) + l]);
        float dtv = (l == 0) ? 0.f : (tc - tprev);
        tprev = tc;
        float mi = (float)mask[(size_t)((b << 8) + l) * 512 + h];
        float delta = dtv + (1.f - mprev) * dprev;
        float gx = __expf(-fmaxf(wg * delta + bg, 0.f));
        float xi = sf(Cmat[(l << 9) + h]);
        float xh = mi * xi + (1.f - mi) * (gx * xlast + (1.f - gx) * xm);
        size_t row = (size_t)ll * 128 + b;           // l-major chunk row
        Xcat[row * 1024 + h]       = f2bf(xh);
        Xcat[row * 1024 + 512 + h] = f2bf(mi);
        Dbuf[row * 512 + h]        = f2bf(delta);
        xlast = mi * xi + (1.f - mi) * xlast;
        dprev = delta; mprev = mi;
    }
    xlastC[g] = xlast; dprevC[g] = dprev; mprevC[g] = mprev; tprevC[g] = tprev;
}

// ---------------- tiled MFMA GEMM, A (MxK) row-major bf16, BT (NxK) row-major bf16 ----
// MODE 0: bf16 out = acc+bias ; MODE 1: fp16 out = exp(-relu(acc+bias)) ;
// MODE 2: f32 out = acc+bias with chunk-row remap (l-major -> (b,l))
template <int MODE>
__global__ __launch_bounds__(256) void gemm_bt(const bf16* __restrict__ A,
                                               const bf16* __restrict__ BT,
                                               const float* __restrict__ bias,
                                               void* __restrict__ Cout,
                                               int N, int K, int q) {
    const int nb = N >> 7;
    int bn = blockIdx.x % nb, bm = blockIdx.x / nb;
    __shared__ bf16 As[4096];   // [kc][row] 16B chunks
    __shared__ bf16 Bs[4096];
    int tid = threadIdx.x, lane = tid & 63, w = tid >> 6;
    int wm = w >> 1, wn = w & 1;
    int quad = lane >> 4, l15 = lane & 15;
    f32x4 acc[4][4];
    #pragma unroll
    for (int i = 0; i < 4; ++i)
        #pragma unroll
        for (int j = 0; j < 4; ++j) acc[i][j] = (f32x4){0.f, 0.f, 0.f, 0.f};

    for (int k0 = 0; k0 < K; k0 += 32) {
        bf16x8 av[2], bv[2];
        #pragma unroll
        for (int cc = 0; cc < 2; ++cc) {
            int c = tid + cc * 256;
            int row = c >> 2, kc = c & 3;
            av[cc] = *(const bf16x8*)(A  + (size_t)(bm * 128 + row) * K + k0 + kc * 8);
            bv[cc] = *(const bf16x8*)(BT + (size_t)(bn * 128 + row) * K + k0 + kc * 8);
        }
        __syncthreads();
        #pragma unroll
        for (int cc = 0; cc < 2; ++cc) {
            int c = tid + cc * 256;
            int row = c >> 2, kc = c & 3;
            *(bf16x8*)&As[(kc * 128 + row) * 8] = av[cc];
            *(bf16x8*)&Bs[(kc * 128 + row) * 8] = bv[cc];
        }
        __syncthreads();
        bf16x8 af[4], bfr[4];
        #pragma unroll
        for (int mt = 0; mt < 4; ++mt)
            af[mt] = *(const bf16x8*)&As[(quad * 128 + wm * 64 + mt * 16 + l15) * 8];
        #pragma unroll
        for (int nt = 0; nt < 4; ++nt)
            bfr[nt] = *(const bf16x8*)&Bs[(quad * 128 + wn * 64 + nt * 16 + l15) * 8];
        #pragma unroll
        for (int mt = 0; mt < 4; ++mt)
            #pragma unroll
            for (int nt = 0; nt < 4; ++nt)
                acc[mt][nt] = MFMA16(af[mt], bfr[nt], acc[mt][nt]);
    }
    int row0 = bm * 128 + wm * 64, col0 = bn * 128 + wn * 64;
    #pragma unroll
    for (int mt = 0; mt < 4; ++mt) {
        #pragma unroll
        for (int nt = 0; nt < 4; ++nt) {
            int col = col0 + nt * 16 + l15;
            float bvf = sf(bias[col]);
            #pragma unroll
            for (int r = 0; r < 4; ++r) {
                int row = row0 + mt * 16 + quad * 4 + r;
                float v = acc[mt][nt][r] + bvf;
                if (MODE == 1)
                    ((__half*)Cout)[(size_t)row * N + col] = __float2half(__expf(-fmaxf(v, 0.f)));
                else if (MODE == 2) {
                    int bb = row & 127, lloc = row >> 7;
                    ((float*)Cout)[(size_t)((bb << 8) + q * CH + lloc) * N + col] = v;
                } else
                    ((bf16*)Cout)[(size_t)row * N + col] = f2bf(v);
            }
        }
    }
}

// ---------------- sequential h-scan over one 32-step chunk ----------------
// 8 clusters x 4 WGs x 512 threads; wave wi owns cols [wi*16,+16) of each gate.
// Protocol: EXACT round-0 proven exchange (agent-scope data stores ->
// __syncthreads vmcnt(0) drain -> tid0 flag post -> tid0 poll-all -> barrier ->
// gather -> barrier). r14 change: strip ops (exchange gather-in + phase C) use
// a LINEAR u64-word mapping: thread t, instr j <-> word w = j*512+t (row =
// j*4 + (t>>7), word-in-row = t&127). Per instruction the 64 lanes of a wave
// touch 512 CONTIGUOUS bytes of LDS (2 lanes/bank = free) instead of round-0's
// 32B-strided pattern (8 lanes/bank-pair). r13 calibrated conflict-cycles ~1:1
// with wall time on this kernel; round-0's 1.44M conflicts ~= 19us/dispatch.
__global__ __launch_bounds__(512, 1) void scan_kernel(
        const bf16* __restrict__ pre,      // (4096,1536) l-major
        const __half* __restrict__ gammaf, // (4096,512) l-major
        const bf16* __restrict__ WhT,      // (1536,512)
        bf16* __restrict__ hseq,           // (4096,512) l-major
        float* __restrict__ hcarry,        // (128,512)
        u64* __restrict__ rbuf,            // [8][2048] u64 (= 16x512 bf16 tile)
        u64* __restrict__ hnbuf,           // [8][2048]
        unsigned* __restrict__ ctr) {      // this chunk's slot (512 uints, zeroed)
    int bx = blockIdx.x;
    int c = bx & 7, w = bx >> 3;           // cluster, WG-in-cluster (0..3)
    int tid = threadIdx.x, lane = tid & 63, v = tid >> 6;   // v in [0,8)
    int wi = (w << 3) | v;                 // 0..31: owns cols [wi*16,+16) per gate
    int quad = lane >> 4, l15 = lane & 15;
    __shared__ bf16 hb[16 * 520];          // full h bf16 (MFMA A source) / hn staging
    __shared__ bf16 rh[16 * 520];          // r*h bf16 (MFMA A source)

    // stationary Wh B-fragments: B[n=l15][k=quad*8+j] per kf block of K=32
    bf16x8 whz[16], whr[16], whh[16];
    int col0 = wi * 16;
    #pragma unroll
    for (int kf = 0; kf < 16; ++kf) {
        int n = col0 + l15;
        whz[kf] = *(const bf16x8*)(WhT + (size_t)n * 512 + kf * 32 + quad * 8);
        whr[kf] = *(const bf16x8*)(WhT + (size_t)(512 + n) * 512 + kf * 32 + quad * 8);
        whh[kf] = *(const bf16x8*)(WhT + (size_t)(1024 + n) * 512 + kf * 32 + quad * 8);
    }

    u64* rclu = rbuf  + (size_t)c * 2048;  // word w = row*128 + (col/4)
    u64* hclu = hnbuf + (size_t)c * 2048;
    const unsigned short* gus = (const unsigned short*)gammaf;
    unsigned* fA = ctr + c * 64;           // 4 flag words per phase per cluster
    unsigned* fB = ctr + c * 64 + 32;

    // init: hb = bf16(hcarry * gamma(step 0)); owned f32 state in hfo
    for (int i = tid; i < 16 * 512; i += 512) {
        int row = i >> 9, col = i & 511;
        int brow = c * 16 + row;
        float g0 = __half2float(gammaf[(size_t)brow * 512 + col]);
        hb[row * 520 + col] = f2bf(hcarry[(size_t)brow * 512 + col] * g0);
    }
    float hfo[4];
    #pragma unroll
    for (int r = 0; r < 4; ++r) {
        int brow = c * 16 + quad * 4 + r;
        int cc = col0 + l15;
        float g0 = __half2float(gammaf[(size_t)brow * 512 + cc]);
        hfo[r] = hcarry[(size_t)brow * 512 + cc] * g0;
    }
    __syncthreads();

    // publish mapping (own-region words, contiguous per row): free of conflicts
    int rrow = tid >> 5, rword = tid & 31;
    // linear strip mapping: word w = j*512 + tid; row = j*4 + rj0; col-word cw
    int rj0 = tid >> 7, cw = tid & 127;
    int sreg = cw >> 5;                    // producing WG of this word column
    bool own = (sreg == w);

    for (int t = 0; t < CH; ++t) {
        unsigned ep = (unsigned)(t + 1);
        bool lastt = (t == CH - 1);
        // ---- register prefetch (plain cached loads; read-only, stays warm) ----
        float pz[4], prr[4], ph[4], gow[4];
        #pragma unroll
        for (int r = 0; r < 4; ++r) {
            int brow = c * 16 + quad * 4 + r;
            size_t pb = ((size_t)t * 128 + brow) * 1536;
            int cc = col0 + l15;
            pz[r]  = bf2f(pre[pb + cc]);
            prr[r] = bf2f(pre[pb + 512 + cc]);
            ph[r]  = bf2f(pre[pb + 1024 + cc]);
            gow[r] = lastt ? 1.f
                   : __half2float(gammaf[((size_t)(t + 1) * 128 + brow) * 512 + cc]);
        }
        u64 gv[4];                         // 4 gammas per strip word (linear map)
        {
            size_t gstep = (size_t)(lastt ? t : t + 1) * 128;
            #pragma unroll
            for (int j = 0; j < 4; ++j) {
                int rowj = j * 4 + rj0;
                gv[j] = *(const u64*)(gus + (gstep + c * 16 + rowj) * 512 + cw * 4);
            }
        }
        // ---- phase A: z local; rh(own cols) = bf16(sigmoid(r) * h) into LDS ----
        f32x4 az = (f32x4){0.f,0.f,0.f,0.f}, ar = az;
        #pragma unroll
        for (int kf = 0; kf < 16; ++kf) {
            bf16x8 a = *(const bf16x8*)&hb[l15 * 520 + kf * 32 + quad * 8];
            az = MFMA16(a, whz[kf], az);
            ar = MFMA16(a, whr[kf], ar);
        }
        float zv[4];
        #pragma unroll
        for (int r = 0; r < 4; ++r) {
            zv[r] = 1.f / (1.f + __expf(-(az[r] + pz[r])));
            float rv = 1.f / (1.f + __expf(-(ar[r] + prr[r])));
            rh[(quad * 4 + r) * 520 + col0 + l15] = f2bf(rv * hfo[r]);
        }
        __syncthreads();                   // [B1] own rh cols in LDS
        // publish own rh region: 1 u64/thread, relaxed agent atomic (LLC store)
        {
            u64 wv = *(const u64*)&rh[rrow * 520 + w * 128 + rword * 4];
            __hip_atomic_store(&rclu[rrow * 128 + w * 32 + rword], wv, RLXA);
        }
        __syncthreads();                   // vmcnt(0): stores landed at LLC
        if (tid == 0) {
            __hip_atomic_store(&fA[w], ep, RLXA);
            int guard = 0;
            for (;;) {
                bool ok = true;
                #pragma unroll
                for (int j = 0; j < 4; ++j)
                    ok &= (__hip_atomic_load(&fA[j], RLXA) >= ep);
                if (ok || ++guard >= (1 << 16)) break;
                __builtin_amdgcn_s_sleep(1);
            }
        }
        __syncthreads();
        // gather peer rh words (linear map: contiguous LDS writes, free)
        if (!own) {
            #pragma unroll
            for (int j = 0; j < 4; ++j) {
                u64 wv = __hip_atomic_load(&rclu[j * 512 + tid], RLXA);
                *(u64*)&rh[(j * 4 + rj0) * 520 + cw * 4] = wv;
            }
        }
        __syncthreads();
        // ---- phase B: ht = tanh(pre3 + rh @ Wh3); hn; stage into hb ----
        f32x4 ah = (f32x4){0.f,0.f,0.f,0.f};
        #pragma unroll
        for (int kf = 0; kf < 16; ++kf) {
            bf16x8 a = *(const bf16x8*)&rh[l15 * 520 + kf * 32 + quad * 8];
            ah = MFMA16(a, whh[kf], ah);
        }
        #pragma unroll
        for (int r = 0; r < 4; ++r) {
            int row = quad * 4 + r;
            int cc = col0 + l15;
            float x = ah[r] + ph[r];
            float e = __expf(-2.f * fabsf(x));
            float th = copysignf((1.f - e) / (1.f + e), x);
            float hn = (1.f - zv[r]) * hfo[r] + zv[r] * th;
            hb[row * 520 + cc] = f2bf(hn);
            if (lastt) {
                int brow = c * 16 + row;
                __builtin_nontemporal_store(hn, &hcarry[(size_t)brow * 512 + cc]);
            }
            hfo[r] = hn * gow[r];
        }
        __syncthreads();
        // publish own hn region
        {
            u64 wv = *(const u64*)&hb[rrow * 520 + w * 128 + rword * 4];
            __hip_atomic_store(&hclu[rrow * 128 + w * 32 + rword], wv, RLXA);
        }
        __syncthreads();                   // vmcnt(0) drain before flag
        if (tid == 0) {
            __hip_atomic_store(&fB[w], ep, RLXA);
            int guard = 0;
            for (;;) {
                bool ok = true;
                #pragma unroll
                for (int j = 0; j < 4; ++j)
                    ok &= (__hip_atomic_load(&fB[j], RLXA) >= ep);
                if (ok || ++guard >= (1 << 16)) break;
                __builtin_amdgcn_s_sleep(1);
            }
        }
        __syncthreads();
        // ---- phase C (linear map): gather hn, write hseq (w0), gamma -> hb ----
        u64 hw[4];
        #pragma unroll
        for (int j = 0; j < 4; ++j) {
            if (own) hw[j] = *(const u64*)&hb[(j * 4 + rj0) * 520 + cw * 4];
            else     hw[j] = __hip_atomic_load(&hclu[j * 512 + tid], RLXA);
        }
        if (w == 0) {
            #pragma unroll
            for (int j = 0; j < 4; ++j) {
                int brow = c * 16 + j * 4 + rj0;
                u64* hs = (u64*)&hseq[((size_t)t * 128 + brow) * 512 + cw * 4];
                __builtin_nontemporal_store(hw[j], hs);
            }
        }
        #pragma unroll
        for (int j = 0; j < 4; ++j) {
            short o4[4];
            #pragma unroll
            for (int e = 0; e < 4; ++e) {
                short hv = (short)((hw[j] >> (16 * e)) & 0xFFFF);
                float g = lastt ? 1.f : h2f((unsigned short)((gv[j] >> (16 * e)) & 0xFFFF));
                o4[e] = f2bs(bs2f(hv) * g);
            }
            u64 ov = ((u64)(unsigned short)o4[0]) | ((u64)(unsigned short)o4[1] << 16)
                   | ((u64)(unsigned short)o4[2] << 32) | ((u64)(unsigned short)o4[3] << 48);
            *(u64*)&hb[(j * 4 + rj0) * 520 + cw * 4] = ov;
        }
        __syncthreads();                   // [B4] hb full tile ready for next step
    }
}

// ---------------- launcher ----------------

extern "C" void kernel_launch(void* const* d_in, const int* in_sizes, int n_in,
                              void* d_out, int out_size, void* d_ws, size_t ws_size,
                              hipStream_t stream) {
    const float* C     = (const float*)d_in[0];
    const float* t_in  = (const float*)d_in[1];
    const int*   mask  = (const int*)d_in[2];
    const float* Wx    = (const float*)d_in[3];
    const float* Wh    = (const float*)d_in[4];
    const float* Wm    = (const float*)d_in[5];
    const float* bvec  = (const float*)d_in[6];
    const float* w_gx  = (const float*)d_in[7];
    const float* b_gx  = (const float*)d_in[8];
    const float* W_gh  = (const float*)d_in[9];
    const float* b_gh  = (const float*)d_in[10];
    const float* W_out = (const float*)d_in[11];
    const float* b_out = (const float*)d_in[12];

    char* w = (char*)d_ws;                              // total used: ~41 MB
    unsigned* ctr   = (unsigned*)(w + 0);               //   16384 (8 chunk slots)
    float* hcarry   = (float*)(w + 16384);              //  262144
    float* xmean    = (float*)(w + 278528);             //  262144
    float* xlastC   = (float*)(w + 540672);             //  262144
    float* dprevC   = (float*)(w + 802816);             //  262144
    float* mprevC   = (float*)(w + 1064960);            //  262144
    float* tprevC   = (float*)(w + 1327104);            //  262144
    bf16*  wcatT    = (bf16*)(w + 1589248);             // 3145728
    bf16*  wghT     = (bf16*)(w + 4734976);             //  524288
    bf16*  whT      = (bf16*)(w + 5259264);             // 1572864
    bf16*  woutT    = (bf16*)(w + 6832128);             //  262144
    bf16*  Xcat     = (bf16*)(w + 7094272);             //  8388608 (chunk)
    bf16*  Dbuf     = (bf16*)(w + 15482880);            //  4194304 (chunk)
    bf16*  pre      = (bf16*)(w + 19677184);            // 12582912 (chunk)
    __half* gamma   = (__half*)(w + 32260096);          //  4194304 (chunk)
    bf16*  hseq     = (bf16*)(w + 36454400);            //  4194304 (chunk)
    u64*   rbuf     = (u64*)(w + 40648704);             //   131072
    u64*   hnbuf    = (u64*)(w + 40779776);             //   131072 -> ends 40,910,848

    hipMemsetAsync(w, 0, 278528, stream);               // ctr + hcarry

    build_wcatT<<<6144, 256, 0, stream>>>(Wx, Wm, wcatT);
    transpose_f2b<<<1024, 256, 0, stream>>>(W_gh, wghT, 512, 512);
    transpose_f2b<<<3072, 256, 0, stream>>>(Wh, whT, 512, 1536);
    transpose_f2b<<<512, 256, 0, stream>>>(W_out, woutT, 512, 256);
    xmean_kernel<<<256, 256, 0, stream>>>(mask, C, xmean);

    for (int q = 0; q < NQ; ++q) {
        prep_kernel<<<256, 256, 0, stream>>>(mask, C, t_in, w_gx, b_gx, xmean,
                                             xlastC, dprevC, mprevC, tprevC,
                                             Xcat, Dbuf, q);
        gemm_bt<0><<<32 * 12, 256, 0, stream>>>(Xcat, wcatT, bvec, (void*)pre, 1536, 1024, q);
        gemm_bt<1><<<32 * 4, 256, 0, stream>>>(Dbuf, wghT, b_gh, (void*)gamma, 512, 512, q);
        scan_kernel<<<32, 512, 0, stream>>>(pre, gamma, whT, hseq, hcarry,
                                            rbuf, hnbuf, ctr + q * 512);
        gemm_bt<2><<<32 * 2, 256, 0, stream>>>(hseq, woutT, b_out, d_out, 256, 512, q);
    }
}

// Round 7
// 2963.012 us; speedup vs baseline: 1.2013x; 1.2013x over previous
//
#include <hip/hip_runtime.h>
#include <hip/hip_bf16.h>
#include <hip/hip_fp16.h>
#include <stdint.h>

typedef short bf16x8 __attribute__((ext_vector_type(8)));
typedef unsigned short u16x8 __attribute__((ext_vector_type(8)));
typedef float f32x4  __attribute__((ext_vector_type(4)));
typedef __hip_bfloat16 bf16;
typedef unsigned long long u64;

#define MFMA16(a,b,c) __builtin_amdgcn_mfma_f32_16x16x32_bf16((a),(b),(c),0,0,0)

__device__ __forceinline__ float bf2f(bf16 x){ return __bfloat162float(x); }
__device__ __forceinline__ bf16  f2bf(float x){ return __float2bfloat16(x); }
__device__ __forceinline__ short f2bs(float x){ bf16 t = __float2bfloat16(x); return *(short*)&t; }
__device__ __forceinline__ float bs2f(short s){ bf16 t; *(short*)&t = s; return __bfloat162float(t); }
__device__ __forceinline__ float h2f(unsigned short u){ __half t; *(unsigned short*)&t = u; return __half2float(t); }
// sanitize raw f32 inputs: kill NaN/inf
__device__ __forceinline__ float sf(float x){ return (fabsf(x) < 1e30f) ? x : 0.f; }

// Problem: B=128, L=256, H=512, OUT=256. All I/O float32. Chunked: 8 x 32 steps.
#define NB   128
#define NL   256
#define CH   32     // steps per chunk
#define MCH  4096   // rows per chunk = CH*NB
#define NQ   8      // chunks

#define RLXA __ATOMIC_RELAXED, __HIP_MEMORY_SCOPE_AGENT

// ---------------- weight preprocessing (f32 in -> bf16 internal) ----------------

__global__ void build_wcatT(const float* __restrict__ Wx, const float* __restrict__ Wm,
                            bf16* __restrict__ dst) {
    int i = blockIdx.x * 256 + threadIdx.x;
    if (i >= 1536 * 1024) return;
    int n = i >> 10, k = i & 1023;
    float v = (k < 512) ? Wx[k * 1536 + n] : Wm[(k - 512) * 1536 + n];
    dst[i] = f2bf(sf(v));
}

__global__ void transpose_f2b(const float* __restrict__ src, bf16* __restrict__ dst,
                              int R, int C) {
    int i = blockIdx.x * 256 + threadIdx.x;
    if (i >= R * C) return;
    int r = i % R, c = i / R;
    dst[i] = f2bf(sf(src[r * C + c]));
}

// ---------------- x-path (h-independent) ----------------

__global__ void xmean_kernel(const int* __restrict__ mask, const float* __restrict__ Cmat,
                             float* __restrict__ xmean) {
    int g = blockIdx.x * 256 + threadIdx.x;   // (b,h)
    int b = g >> 9, h = g & 511;
    float s = 0.f, cnt = 0.f;
    for (int l = 0; l < NL; ++l) {
        int m = mask[(size_t)((b << 8) + l) * 512 + h];
        if (m) { s += sf(Cmat[(l << 9) + h]); cnt += 1.f; }
    }
    xmean[g] = s / fmaxf(cnt, 1.f);
}

__global__ void prep_kernel(const int* __restrict__ mask, const float* __restrict__ Cmat,
                            const float* __restrict__ t_in,
                            const float* __restrict__ w_gx, const float* __restrict__ b_gx,
                            const float* __restrict__ xmean,
                            float* __restrict__ xlastC, float* __restrict__ dprevC,
                            float* __restrict__ mprevC, float* __restrict__ tprevC,
                            bf16* __restrict__ Xcat,   // (4096,1024) l-major: [x_hat|m]
                            bf16* __restrict__ Dbuf,   // (4096,512) l-major: delta
                            int q) {
    int g = blockIdx.x * 256 + threadIdx.x;
    int b = g >> 9, h = g & 511;
    float wg = sf(w_gx[h]), bg = sf(b_gx[h]);
    float xm = xmean[g];
    float xlast, dprev, mprev, tprev;
    if (q == 0) { xlast = xm; dprev = 0.f; mprev = 1.f; tprev = 0.f; }
    else { xlast = xlastC[g]; dprev = dprevC[g]; mprev = mprevC[g]; tprev = tprevC[g]; }
    for (int ll = 0; ll < CH; ++ll) {
        int l = q * CH + ll;
        float tc = sf(t_in[(b << 8) + l]);
        float dtv = (l == 0) ? 0.f : (tc - tprev);
        tprev = tc;
        float mi = (float)mask[(size_t)((b << 8) + l) * 512 + h];
        float delta = dtv + (1.f - mprev) * dprev;
        float gx = __expf(-fmaxf(wg * delta + bg, 0.f));
        float xi = sf(Cmat[(l << 9) + h]);
        float xh = mi * xi + (1.f - mi) * (gx * xlast + (1.f - gx) * xm);
        size_t row = (size_t)ll * 128 + b;           // l-major chunk row
        Xcat[row * 1024 + h]       = f2bf(xh);
        Xcat[row * 1024 + 512 + h] = f2bf(mi);
        Dbuf[row * 512 + h]        = f2bf(delta);
        xlast = mi * xi + (1.f - mi) * xlast;
        dprev = delta; mprev = mi;
    }
    xlastC[g] = xlast; dprevC[g] = dprev; mprevC[g] = mprev; tprevC[g] = tprev;
}

// ---------------- tiled MFMA GEMM, A (MxK) row-major bf16, BT (NxK) row-major bf16 ----
// MODE 0: bf16 out = acc+bias ; MODE 1: fp16 out = exp(-relu(acc+bias)) ;
// MODE 2: f32 out = acc+bias with chunk-row remap (l-major -> (b,l))
template <int MODE>
__global__ __launch_bounds__(256) void gemm_bt(const bf16* __restrict__ A,
                                               const bf16* __restrict__ BT,
                                               const float* __restrict__ bias,
                                               void* __restrict__ Cout,
                                               int N, int K, int q) {
    const int nb = N >> 7;
    int bn = blockIdx.x % nb, bm = blockIdx.x / nb;
    __shared__ bf16 As[4096];   // [kc][row] 16B chunks
    __shared__ bf16 Bs[4096];
    int tid = threadIdx.x, lane = tid & 63, w = tid >> 6;
    int wm = w >> 1, wn = w & 1;
    int quad = lane >> 4, l15 = lane & 15;
    f32x4 acc[4][4];
    #pragma unroll
    for (int i = 0; i < 4; ++i)
        #pragma unroll
        for (int j = 0; j < 4; ++j) acc[i][j] = (f32x4){0.f, 0.f, 0.f, 0.f};

    for (int k0 = 0; k0 < K; k0 += 32) {
        bf16x8 av[2], bv[2];
        #pragma unroll
        for (int cc = 0; cc < 2; ++cc) {
            int c = tid + cc * 256;
            int row = c >> 2, kc = c & 3;
            av[cc] = *(const bf16x8*)(A  + (size_t)(bm * 128 + row) * K + k0 + kc * 8);
            bv[cc] = *(const bf16x8*)(BT + (size_t)(bn * 128 + row) * K + k0 + kc * 8);
        }
        __syncthreads();
        #pragma unroll
        for (int cc = 0; cc < 2; ++cc) {
            int c = tid + cc * 256;
            int row = c >> 2, kc = c & 3;
            *(bf16x8*)&As[(kc * 128 + row) * 8] = av[cc];
            *(bf16x8*)&Bs[(kc * 128 + row) * 8] = bv[cc];
        }
        __syncthreads();
        bf16x8 af[4], bfr[4];
        #pragma unroll
        for (int mt = 0; mt < 4; ++mt)
            af[mt] = *(const bf16x8*)&As[(quad * 128 + wm * 64 + mt * 16 + l15) * 8];
        #pragma unroll
        for (int nt = 0; nt < 4; ++nt)
            bfr[nt] = *(const bf16x8*)&Bs[(quad * 128 + wn * 64 + nt * 16 + l15) * 8];
        #pragma unroll
        for (int mt = 0; mt < 4; ++mt)
            #pragma unroll
            for (int nt = 0; nt < 4; ++nt)
                acc[mt][nt] = MFMA16(af[mt], bfr[nt], acc[mt][nt]);
    }
    int row0 = bm * 128 + wm * 64, col0 = bn * 128 + wn * 64;
    #pragma unroll
    for (int mt = 0; mt < 4; ++mt) {
        #pragma unroll
        for (int nt = 0; nt < 4; ++nt) {
            int col = col0 + nt * 16 + l15;
            float bvf = sf(bias[col]);
            #pragma unroll
            for (int r = 0; r < 4; ++r) {
                int row = row0 + mt * 16 + quad * 4 + r;
                float v = acc[mt][nt][r] + bvf;
                if (MODE == 1)
                    ((__half*)Cout)[(size_t)row * N + col] = __float2half(__expf(-fmaxf(v, 0.f)));
                else if (MODE == 2) {
                    int bb = row & 127, lloc = row >> 7;
                    ((float*)Cout)[(size_t)((bb << 8) + q * CH + lloc) * N + col] = v;
                } else
                    ((bf16*)Cout)[(size_t)row * N + col] = f2bf(v);
            }
        }
    }
}

// ---------------- sequential h-scan over one 32-step chunk ----------------
// 8 clusters x 4 WGs x 512 threads; wave wi owns cols [wi*16,+16) of each gate.
// Base: byte-exact round-0 kernel (proven 255us/dispatch). r15 delta: the flag
// protocol keeps {agent-scope data stores -> __syncthreads vmcnt(0) drain ->
// tid0 flag post}, but the POLL is DISTRIBUTED: each gathering thread polls
// only fA[pregion] (its strip's producer) and gathers as soon as it flips.
// Removes one barrier + the tid0 serial poll-all per exchange.
// Safety (collective observation): data visibility per gather = producer's
// drain-barrier precedes its flag post; observer's loads follow its flag
// observation (same causal chain as round-0). Slot-reuse gating: within each
// WG every peer flag is observed >= ep by 128 threads and the next
// __syncthreads joins those observations, so "all fB >= ep gates rclu reuse"
// and "all fA >= ep+1 gates hclu reuse" hold exactly as in round-0.
__global__ __launch_bounds__(512, 1) void scan_kernel(
        const bf16* __restrict__ pre,      // (4096,1536) l-major
        const __half* __restrict__ gammaf, // (4096,512) l-major
        const bf16* __restrict__ WhT,      // (1536,512)
        bf16* __restrict__ hseq,           // (4096,512) l-major
        float* __restrict__ hcarry,        // (128,512)
        u64* __restrict__ rbuf,            // [8][2048] u64 (= 16x512 bf16 tile)
        u64* __restrict__ hnbuf,           // [8][2048]
        unsigned* __restrict__ ctr) {      // this chunk's slot (512 uints, zeroed)
    int bx = blockIdx.x;
    int c = bx & 7, w = bx >> 3;           // cluster, WG-in-cluster (0..3)
    int tid = threadIdx.x, lane = tid & 63, v = tid >> 6;   // v in [0,8)
    int wi = (w << 3) | v;                 // 0..31: owns cols [wi*16,+16) per gate
    int quad = lane >> 4, l15 = lane & 15;
    __shared__ bf16 hb[16 * 520];          // full h bf16 (MFMA A source) / hn staging
    __shared__ bf16 rh[16 * 520];          // r*h bf16 (MFMA A source)

    // stationary Wh B-fragments: B[n=l15][k=quad*8+j] per kf block of K=32
    bf16x8 whz[16], whr[16], whh[16];
    int col0 = wi * 16;
    #pragma unroll
    for (int kf = 0; kf < 16; ++kf) {
        int n = col0 + l15;
        whz[kf] = *(const bf16x8*)(WhT + (size_t)n * 512 + kf * 32 + quad * 8);
        whr[kf] = *(const bf16x8*)(WhT + (size_t)(512 + n) * 512 + kf * 32 + quad * 8);
        whh[kf] = *(const bf16x8*)(WhT + (size_t)(1024 + n) * 512 + kf * 32 + quad * 8);
    }

    u64* rclu = rbuf  + (size_t)c * 2048;  // 16 rows x 128 words
    u64* hclu = hnbuf + (size_t)c * 2048;
    const unsigned short* gus = (const unsigned short*)gammaf;
    unsigned* fA = ctr + c * 64;           // 4 flag words per phase per cluster
    unsigned* fB = ctr + c * 64 + 32;

    // init: hb = bf16(hcarry * gamma(step 0)); owned f32 state in hfo
    for (int i = tid; i < 16 * 512; i += 512) {
        int row = i >> 9, col = i & 511;
        int brow = c * 16 + row;
        float g0 = __half2float(gammaf[(size_t)brow * 512 + col]);
        hb[row * 520 + col] = f2bf(hcarry[(size_t)brow * 512 + col] * g0);
    }
    float hfo[4];
    #pragma unroll
    for (int r = 0; r < 4; ++r) {
        int brow = c * 16 + quad * 4 + r;
        int cc = col0 + l15;
        float g0 = __half2float(gammaf[(size_t)brow * 512 + cc]);
        hfo[r] = hcarry[(size_t)brow * 512 + cc] * g0;
    }
    __syncthreads();

    // repack mapping (own-region words): 16 rows x 32 words of own 128-col region
    int rrow = tid >> 5, rword = tid & 31;
    // strip mapping (exchange-in / phase C): row prow, 16 cols from one region
    int prow = tid >> 5, pc16 = tid & 31, pcol = pc16 << 4, pregion = pc16 >> 3;
    unsigned* myfA = &fA[pregion];
    unsigned* myfB = &fB[pregion];

    for (int t = 0; t < CH; ++t) {
        unsigned ep = (unsigned)(t + 1);
        bool lastt = (t == CH - 1);
        // ---- register prefetch (plain cached loads; read-only, stays warm) ----
        float pz[4], prr[4], ph[4], gow[4];
        #pragma unroll
        for (int r = 0; r < 4; ++r) {
            int brow = c * 16 + quad * 4 + r;
            size_t pb = ((size_t)t * 128 + brow) * 1536;
            int cc = col0 + l15;
            pz[r]  = bf2f(pre[pb + cc]);
            prr[r] = bf2f(pre[pb + 512 + cc]);
            ph[r]  = bf2f(pre[pb + 1024 + cc]);
            gow[r] = lastt ? 1.f
                   : __half2float(gammaf[((size_t)(t + 1) * 128 + brow) * 512 + cc]);
        }
        u16x8 gt[2];
        {
            size_t gb = ((size_t)(lastt ? t : t + 1) * 128 + c * 16 + prow) * 512 + pcol;
            #pragma unroll
            for (int j = 0; j < 2; ++j) gt[j] = *(const u16x8*)(gus + gb + j * 8);
        }
        // ---- phase A: z local; rh(own cols) = bf16(sigmoid(r) * h) into LDS ----
        f32x4 az = (f32x4){0.f,0.f,0.f,0.f}, ar = az;
        #pragma unroll
        for (int kf = 0; kf < 16; ++kf) {
            bf16x8 a = *(const bf16x8*)&hb[l15 * 520 + kf * 32 + quad * 8];
            az = MFMA16(a, whz[kf], az);
            ar = MFMA16(a, whr[kf], ar);
        }
        float zv[4];
        #pragma unroll
        for (int r = 0; r < 4; ++r) {
            zv[r] = 1.f / (1.f + __expf(-(az[r] + pz[r])));
            float rv = 1.f / (1.f + __expf(-(ar[r] + prr[r])));
            rh[(quad * 4 + r) * 520 + col0 + l15] = f2bf(rv * hfo[r]);
        }
        __syncthreads();                   // [B1] own rh cols in LDS
        // publish own rh region: 1 u64/thread, relaxed agent atomic (LLC store)
        {
            u64 wv = *(const u64*)&rh[rrow * 520 + w * 128 + rword * 4];
            __hip_atomic_store(&rclu[rrow * 128 + w * 32 + rword], wv, RLXA);
        }
        __syncthreads();                   // vmcnt(0): stores landed at LLC
        if (tid == 0) __hip_atomic_store(&fA[w], ep, RLXA);
        // distributed poll + gather: each thread waits only on its producer
        if (pregion != w) {
            int guard = 0;
            while (__hip_atomic_load(myfA, RLXA) < ep) {
                if (++guard >= (1 << 16)) break;
                __builtin_amdgcn_s_sleep(1);
            }
            #pragma unroll
            for (int j = 0; j < 4; ++j) {
                u64 wv = __hip_atomic_load(&rclu[prow * 128 + pc16 * 4 + j], RLXA);
                *(u64*)&rh[prow * 520 + pcol + j * 4] = wv;
            }
        }
        __syncthreads();                   // join: full rh tile + collective obs
        // ---- phase B: ht = tanh(pre3 + rh @ Wh3); hn; stage into hb ----
        f32x4 ah = (f32x4){0.f,0.f,0.f,0.f};
        #pragma unroll
        for (int kf = 0; kf < 16; ++kf) {
            bf16x8 a = *(const bf16x8*)&rh[l15 * 520 + kf * 32 + quad * 8];
            ah = MFMA16(a, whh[kf], ah);
        }
        #pragma unroll
        for (int r = 0; r < 4; ++r) {
            int row = quad * 4 + r;
            int cc = col0 + l15;
            float x = ah[r] + ph[r];
            float e = __expf(-2.f * fabsf(x));
            float th = copysignf((1.f - e) / (1.f + e), x);
            float hn = (1.f - zv[r]) * hfo[r] + zv[r] * th;
            hb[row * 520 + cc] = f2bf(hn);
            if (lastt) {
                int brow = c * 16 + row;
                __builtin_nontemporal_store(hn, &hcarry[(size_t)brow * 512 + cc]);
            }
            hfo[r] = hn * gow[r];
        }
        __syncthreads();                   // [B3] own hn cols in LDS
        // publish own hn region
        {
            u64 wv = *(const u64*)&hb[rrow * 520 + w * 128 + rword * 4];
            __hip_atomic_store(&hclu[rrow * 128 + w * 32 + rword], wv, RLXA);
        }
        __syncthreads();                   // vmcnt(0) drain before flag
        if (tid == 0) __hip_atomic_store(&fB[w], ep, RLXA);
        // ---- phase C: distributed poll+gather hn, write hseq (w0), gamma -> hb
        u64 hw[4];
        if (pregion != w) {
            int guard = 0;
            while (__hip_atomic_load(myfB, RLXA) < ep) {
                if (++guard >= (1 << 16)) break;
                __builtin_amdgcn_s_sleep(1);
            }
            #pragma unroll
            for (int j = 0; j < 4; ++j)
                hw[j] = __hip_atomic_load(&hclu[prow * 128 + pc16 * 4 + j], RLXA);
        } else {
            #pragma unroll
            for (int j = 0; j < 4; ++j)
                hw[j] = *(const u64*)&hb[prow * 520 + pcol + j * 4];
        }
        if (w == 0) {
            int brow = c * 16 + prow;
            u64* hs = (u64*)&hseq[((size_t)t * 128 + brow) * 512 + pcol];
            #pragma unroll
            for (int j = 0; j < 4; ++j) __builtin_nontemporal_store(hw[j], &hs[j]);
        }
        #pragma unroll
        for (int j = 0; j < 4; ++j) {
            u16x8* gp = (u16x8*)&gt[0];    // 16 gammas for this strip
            short o4[4];
            #pragma unroll
            for (int e = 0; e < 4; ++e) {
                short hv = (short)((hw[j] >> (16 * e)) & 0xFFFF);
                float g = lastt ? 1.f : h2f(((unsigned short*)gp)[j * 4 + e]);
                o4[e] = f2bs(bs2f(hv) * g);
            }
            u64 ov = ((u64)(unsigned short)o4[0]) | ((u64)(unsigned short)o4[1] << 16)
                   | ((u64)(unsigned short)o4[2] << 32) | ((u64)(unsigned short)o4[3] << 48);
            *(u64*)&hb[prow * 520 + pcol + j * 4] = ov;
        }
        __syncthreads();                   // [B4] hb full tile ready for next step
    }
}

// ---------------- launcher ----------------

extern "C" void kernel_launch(void* const* d_in, const int* in_sizes, int n_in,
                              void* d_out, int out_size, void* d_ws, size_t ws_size,
                              hipStream_t stream) {
    const float* C     = (const float*)d_in[0];
    const float* t_in  = (const float*)d_in[1];
    const int*   mask  = (const int*)d_in[2];
    const float* Wx    = (const float*)d_in[3];
    const float* Wh    = (const float*)d_in[4];
    const float* Wm    = (const float*)d_in[5];
    const float* bvec  = (const float*)d_in[6];
    const float* w_gx  = (const float*)d_in[7];
    const float* b_gx  = (const float*)d_in[8];
    const float* W_gh  = (const float*)d_in[9];
    const float* b_gh  = (const float*)d_in[10];
    const float* W_out = (const float*)d_in[11];
    const float* b_out = (const float*)d_in[12];

    char* w = (char*)d_ws;                              // total used: ~41 MB
    unsigned* ctr   = (unsigned*)(w + 0);               //   16384 (8 chunk slots)
    float* hcarry   = (float*)(w + 16384);              //  262144
    float* xmean    = (float*)(w + 278528);             //  262144
    float* xlastC   = (float*)(w + 540672);             //  262144
    float* dprevC   = (float*)(w + 802816);             //  262144
    float* mprevC   = (float*)(w + 1064960);            //  262144
    float* tprevC   = (float*)(w + 1327104);            //  262144
    bf16*  wcatT    = (bf16*)(w + 1589248);             // 3145728
    bf16*  wghT     = (bf16*)(w + 4734976);             //  524288
    bf16*  whT      = (bf16*)(w + 5259264);             // 1572864
    bf16*  woutT    = (bf16*)(w + 6832128);             //  262144
    bf16*  Xcat     = (bf16*)(w + 7094272);             //  8388608 (chunk)
    bf16*  Dbuf     = (bf16*)(w + 15482880);            //  4194304 (chunk)
    bf16*  pre      = (bf16*)(w + 19677184);            // 12582912 (chunk)
    __half* gamma   = (__half*)(w + 32260096);          //  4194304 (chunk)
    bf16*  hseq     = (bf16*)(w + 36454400);            //  4194304 (chunk)
    u64*   rbuf     = (u64*)(w + 40648704);             //   131072
    u64*   hnbuf    = (u64*)(w + 40779776);             //   131072 -> ends 40,910,848

    hipMemsetAsync(w, 0, 278528, stream);               // ctr + hcarry

    build_wcatT<<<6144, 256, 0, stream>>>(Wx, Wm, wcatT);
    transpose_f2b<<<1024, 256, 0, stream>>>(W_gh, wghT, 512, 512);
    transpose_f2b<<<3072, 256, 0, stream>>>(Wh, whT, 512, 1536);
    transpose_f2b<<<512, 256, 0, stream>>>(W_out, woutT, 512, 256);
    xmean_kernel<<<256, 256, 0, stream>>>(mask, C, xmean);

    for (int q = 0; q < NQ; ++q) {
        prep_kernel<<<256, 256, 0, stream>>>(mask, C, t_in, w_gx, b_gx, xmean,
                                             xlastC, dprevC, mprevC, tprevC,
                                             Xcat, Dbuf, q);
        gemm_bt<0><<<32 * 12, 256, 0, stream>>>(Xcat, wcatT, bvec, (void*)pre, 1536, 1024, q);
        gemm_bt<1><<<32 * 4, 256, 0, stream>>>(Dbuf, wghT, b_gh, (void*)gamma, 512, 512, q);
        scan_kernel<<<32, 512, 0, stream>>>(pre, gamma, whT, hseq, hcarry,
                                            rbuf, hnbuf, ctr + q * 512);
        gemm_bt<2><<<32 * 2, 256, 0, stream>>>(hseq, woutT, b_out, d_out, 256, 512, q);
    }
}